// Round 13
// baseline (20.356 us; speedup 1.0000x reference)
//
#include <hip/hip_runtime.h>
#include <math.h>

typedef unsigned uns;

// v_sad_u8 with A from SGPR (VOP3 src0 may be scalar): d = c + sum|a.b[k]-b.b[k]|
__device__ __forceinline__ uns sad8_sv(uns a_s, uns b, uns c) {
    uns d;
    asm("v_sad_u8 %0, %1, %2, %3" : "=v"(d) : "s"(a_s), "v"(b), "v"(c));
    return d;
}

// ---- prepass: sigmoid -> u8; A row-major, B transposed [chunk][row]; row sums ----
__global__ __launch_bounds__(256)
void prepass(const float* __restrict__ x1, const float* __restrict__ x2,
             uns* __restrict__ Aq, uns* __restrict__ Bt,
             float* __restrict__ rs) {
    const int wid = threadIdx.x >> 6, lane = threadIdx.x & 63;
    const int r = blockIdx.x * 4 + wid;            // 0..2047
    const bool isA = (r < 1024);
    const int row = isA ? r : (r - 1024);
    const float* src = (isA ? x1 : x2) + (size_t)row * 256;

    float4 g = *(const float4*)(src + 4 * lane);
    const float k = 255.0f;
    uns q0 = (uns)(k / (1.0f + __expf(-g.x)) + 0.5f);
    uns q1 = (uns)(k / (1.0f + __expf(-g.y)) + 0.5f);
    uns q2 = (uns)(k / (1.0f + __expf(-g.z)) + 0.5f);
    uns q3 = (uns)(k / (1.0f + __expf(-g.w)) + 0.5f);
    const uns packed = q0 | (q1 << 8) | (q2 << 16) | (q3 << 24);

    if (isA) {
        Aq[(size_t)row * 64 + lane] = packed;                    // row-major
    } else {
        // transposed: dword (lane&3) of uint4 chunk (lane>>2) of column `row`
        Bt[(size_t)(lane >> 2) * 4096 + (size_t)row * 4 + (lane & 3)] = packed;
    }

    int sum = (int)(q0 + q1 + q2 + q3);
    #pragma unroll
    for (int s = 32; s >= 1; s >>= 1)
        sum += __shfl_xor(sum, s, 64);
    if (lane == 0) rs[r] = (float)sum;             // <= 65280: f32-exact
}

// ---- main: LDS-free, barrier-free. Wave = 4 rows x 64 cols.
// B col in VGPRs (coalesced transposed load, once); A rows via scalar pipe. ----
__global__ __launch_bounds__(256, 4)
void jaccard_main(const uns* __restrict__ Aq, const uint4* __restrict__ Bt,
                  const float* __restrict__ rs, float* __restrict__ out) {
    const int bi   = blockIdx.x;          // 0..63 : 16-row stripes
    const int bj   = blockIdx.y;          // 0..15 : 64-col stripes
    const int lane = threadIdx.x & 63;
    const int wid  = threadIdx.x >> 6;    // 0..3

    const int col = bj * 64 + lane;

    // ---- B column: 16 chunks x 16B, fully coalesced, loaded once ----
    uint4 bq[16];
    #pragma unroll
    for (int cc = 0; cc < 16; ++cc)
        bq[cc] = Bt[(size_t)cc * 1024 + col];

    const int row0 = __builtin_amdgcn_readfirstlane(bi * 16 + wid * 4);
    const uns* arow = Aq + (size_t)row0 * 64;     // 4 consecutive rows = 256 dwords

    uns acc[4] = {0, 0, 0, 0};
    #pragma unroll
    for (int q = 0; q < 4; ++q) {                 // D-quarter = 64B
        #pragma unroll
        for (int r = 0; r < 4; ++r) {
            const uns* ap = arow + r * 64 + q * 16;    // uniform -> s_load
            uns a = acc[r];
            #pragma unroll
            for (int k = 0; k < 4; ++k) {              // 16B chunk q*4+k
                const uint4 b = bq[q * 4 + k];
                a = sad8_sv(ap[4 * k + 0], b.x, a);
                a = sad8_sv(ap[4 * k + 1], b.y, a);
                a = sad8_sv(ap[4 * k + 2], b.z, a);
                a = sad8_sv(ap[4 * k + 3], b.w, a);
            }
            acc[r] = a;
        }
    }

    // ---- epilogue: inter = (sa+sb-sad)/2 ; union = sa+sb-inter ----
    const float sb = rs[1024 + col];
    float* outT = out + (size_t)1024 * 1024;
    #pragma unroll
    for (int r = 0; r < 4; ++r) {
        const int i = row0 + r;
        const float sa = rs[i];
        const float t  = sa + sb;
        const float in = 0.5f * (t - (float)acc[r]);
        const float v  = in / (t - in);
        out [(size_t)i   * 1024 + col] = v;   // coalesced over lanes
        outT[(size_t)col * 1024 + i]   = v;   // scatter; L2 merges
    }
}

extern "C" void kernel_launch(void* const* d_in, const int* in_sizes, int n_in,
                              void* d_out, int out_size, void* d_ws, size_t ws_size,
                              hipStream_t stream) {
    const float* x1 = (const float*)d_in[0];
    const float* x2 = (const float*)d_in[1];
    float* out = (float*)d_out;

    uns*   Aq = (uns*)d_ws;                         // 256 KB row-major u8 A
    uns*   Bt = Aq + (size_t)1024 * 64;             // 256 KB transposed u8 B
    float* rs = (float*)(Bt + (size_t)1024 * 64);   // 8 KB row sums

    prepass<<<512, 256, 0, stream>>>(x1, x2, Aq, Bt, rs);
    jaccard_main<<<dim3(64, 16), 256, 0, stream>>>(Aq, (const uint4*)Bt, rs, out);
}

// Round 14
// 19.194 us; speedup vs baseline: 1.0606x; 1.0606x over previous
//
#include <hip/hip_runtime.h>
#include <math.h>

#define RSTR  272                 // u8 tile row stride: 17 x 16B groups -> even group spread
#define BOFF  (64 * RSTR)         // 17408
#define LDSZ  (2 * 64 * RSTR)     // 34816 B: static __shared__, tiles only

// v_sad_u8: d = c + sum_k |a.byte[k] - b.byte[k]|
__device__ __forceinline__ unsigned sad8(unsigned a, unsigned b, unsigned c) {
    unsigned d;
    asm("v_sad_u8 %0, %1, %2, %3" : "=v"(d) : "v"(a), "v"(b), "v"(c));
    return d;
}

// quad-perm DPP butterfly add over lane quads (pure VALU, no LDS)
__device__ __forceinline__ unsigned quad_reduce_add(unsigned v) {
    unsigned t = (unsigned)__builtin_amdgcn_mov_dpp((int)v, 0xB1, 0xF, 0xF, false); // [1,0,3,2]
    v += t;
    t = (unsigned)__builtin_amdgcn_mov_dpp((int)v, 0x4E, 0xF, 0xF, false);          // [2,3,0,1]
    return v + t;
}

// ---- prepass: sigmoid -> u8 (x255, round) + integer row sums (f32-exact) ----
__global__ __launch_bounds__(256)
void prepass(const float* __restrict__ x1, const float* __restrict__ x2,
             unsigned* __restrict__ Aq, unsigned* __restrict__ Bq,
             float* __restrict__ rs) {
    const int wid = threadIdx.x >> 6, lane = threadIdx.x & 63;
    const int r = blockIdx.x * 4 + wid;            // 0..2047
    const bool isA = (r < 1024);
    const int row = isA ? r : (r - 1024);
    const float* src = (isA ? x1 : x2) + (size_t)row * 256;

    float4 g = *(const float4*)(src + 4 * lane);
    const float k = 255.0f;
    unsigned q0 = (unsigned)(k / (1.0f + __expf(-g.x)) + 0.5f);
    unsigned q1 = (unsigned)(k / (1.0f + __expf(-g.y)) + 0.5f);
    unsigned q2 = (unsigned)(k / (1.0f + __expf(-g.z)) + 0.5f);
    unsigned q3 = (unsigned)(k / (1.0f + __expf(-g.w)) + 0.5f);

    (isA ? Aq : Bq)[(size_t)row * 64 + lane] = q0 | (q1 << 8) | (q2 << 16) | (q3 << 24);

    int sum = (int)(q0 + q1 + q2 + q3);
    #pragma unroll
    for (int s = 32; s >= 1; s >>= 1)
        sum += __shfl_xor(sum, s, 64);
    if (lane == 0) rs[r] = (float)sum;             // <= 65280: f32-exact
}

// ---- main: quarter-in-quad layout, DPP cross-quarter reduce, no partial LDS ----
__global__ __launch_bounds__(1024, 4)
void jaccard_main(const uint4* __restrict__ Aq, const uint4* __restrict__ Bq,
                  const float* __restrict__ rs, float* __restrict__ out) {
    __shared__ char lds[LDSZ];
    char* ATile = lds;
    char* BTile = lds + BOFF;

    const int bi = blockIdx.x, bj = blockIdx.y;
    const int tid = threadIdx.x;

    // ---- staging: 1 uint4 load + 1 b128 LDS write per thread per tile ----
    {
        const int row = tid >> 4, c16 = tid & 15;          // 64 rows x 16 chunks
        uint4 va = Aq[(size_t)(bi * 64 + row) * 16 + c16];
        *(uint4*)(ATile + row * RSTR + c16 * 16) = va;
        uint4 vb = Bq[(size_t)(bj * 64 + row) * 16 + c16];
        *(uint4*)(BTile + row * RSTR + c16 * 16) = vb;
    }
    __syncthreads();

    // lane roles: ql = D-quarter (bytes [64*ql, 64*ql+64)), tx = spatial col, w = ty
    const int lane = tid & 63;
    const int w    = tid >> 6;      // ty: 0..15
    const int ql   = lane & 3;
    const int tx   = lane >> 2;     // 0..15

    const char* ab = ATile + w  * RSTR + ql * 64;
    const char* bb = BTile + tx * RSTR + ql * 64;

    unsigned acc[4][4] = {};        // [m][n], this lane's quarter partial
    #pragma unroll
    for (int cc = 0; cc < 4; ++cc) {                       // 4 x 16B chunks per quarter
        uint4 av[4], bv[4];
        #pragma unroll
        for (int m = 0; m < 4; ++m)
            av[m] = *(const uint4*)(ab + m * (16 * RSTR) + cc * 16);   // 4 addrs, broadcast
        #pragma unroll
        for (int n = 0; n < 4; ++n)
            bv[n] = *(const uint4*)(bb + n * (16 * RSTR) + cc * 16);   // 64 distinct: 1KB/instr
        #pragma unroll
        for (int m = 0; m < 4; ++m)
            #pragma unroll
            for (int n = 0; n < 4; ++n) {
                unsigned a = acc[m][n];
                a = sad8(av[m].x, bv[n].x, a);
                a = sad8(av[m].y, bv[n].y, a);
                a = sad8(av[m].z, bv[n].z, a);
                a = sad8(av[m].w, bv[n].w, a);
                acc[m][n] = a;
            }
    }

    // ---- cross-quarter reduce in-register (DPP), then lane ql keeps row m=ql ----
    unsigned sd[4];
    #pragma unroll
    for (int n = 0; n < 4; ++n) {
        unsigned r0 = quad_reduce_add(acc[0][n]);
        unsigned r1 = quad_reduce_add(acc[1][n]);
        unsigned r2 = quad_reduce_add(acc[2][n]);
        unsigned r3 = quad_reduce_add(acc[3][n]);
        sd[n] = ql < 2 ? (ql == 0 ? r0 : r1) : (ql == 2 ? r2 : r3);  // static idx + cndmask
    }

    // ---- epilogue: row i = w + 16*ql, cols j0 + 16n ----
    const int i  = bi * 64 + w + 16 * ql;
    const int j0 = bj * 64 + tx;

    const float sa  = rs[i];
    const float sb0 = rs[1024 + j0];
    const float sb1 = rs[1024 + j0 + 16];
    const float sb2 = rs[1024 + j0 + 32];
    const float sb3 = rs[1024 + j0 + 48];

    const float t0 = sa + sb0, t1 = sa + sb1, t2 = sa + sb2, t3 = sa + sb3;
    const float i0 = 0.5f * (t0 - (float)sd[0]);
    const float i1 = 0.5f * (t1 - (float)sd[1]);
    const float i2 = 0.5f * (t2 - (float)sd[2]);
    const float i3 = 0.5f * (t3 - (float)sd[3]);
    const float v0 = i0 / (t0 - i0);
    const float v1 = i1 / (t1 - i1);
    const float v2 = i2 / (t2 - i2);
    const float v3 = i3 / (t3 - i3);

    float* outT = out + (size_t)1024 * 1024;
    out[(size_t)i * 1024 + j0]      = v0;
    out[(size_t)i * 1024 + j0 + 16] = v1;
    out[(size_t)i * 1024 + j0 + 32] = v2;
    out[(size_t)i * 1024 + j0 + 48] = v3;
    outT[(size_t)j0        * 1024 + i] = v0;
    outT[(size_t)(j0 + 16) * 1024 + i] = v1;
    outT[(size_t)(j0 + 32) * 1024 + i] = v2;
    outT[(size_t)(j0 + 48) * 1024 + i] = v3;
}

extern "C" void kernel_launch(void* const* d_in, const int* in_sizes, int n_in,
                              void* d_out, int out_size, void* d_ws, size_t ws_size,
                              hipStream_t stream) {
    const float* x1 = (const float*)d_in[0];
    const float* x2 = (const float*)d_in[1];
    float* out = (float*)d_out;

    unsigned* Aq = (unsigned*)d_ws;                 // 256 KB
    unsigned* Bq = Aq + (size_t)1024 * 64;          // 256 KB
    float*    rs = (float*)(Bq + (size_t)1024 * 64);// 8 KB

    prepass<<<512, 256, 0, stream>>>(x1, x2, Aq, Bq, rs);
    jaccard_main<<<dim3(16, 16), 1024, 0, stream>>>((const uint4*)Aq, (const uint4*)Bq,
                                                    rs, out);
}

// Round 15
// 15.852 us; speedup vs baseline: 1.2842x; 1.2108x over previous
//
#include <hip/hip_runtime.h>
#include <math.h>

#define RSTR  272                  // u8 tile row stride: 17 x 16B groups
#define TILEB (32 * RSTR)          // 8704 B per tile (32 rows)
#define PSTR  136                  // partial stride per spatial lane: 4q*32B + 8 pad

// v_sad_u8: d = c + sum_k |a.byte[k] - b.byte[k]|
__device__ __forceinline__ unsigned sad8(unsigned a, unsigned b, unsigned c) {
    unsigned d;
    asm("v_sad_u8 %0, %1, %2, %3" : "=v"(d) : "v"(a), "v"(b), "v"(c));
    return d;
}

// ---- prepass: sigmoid -> u8 (x255, round) + integer row sums (f32-exact) ----
__global__ __launch_bounds__(256)
void prepass(const float* __restrict__ x1, const float* __restrict__ x2,
             unsigned* __restrict__ Aq, unsigned* __restrict__ Bq,
             float* __restrict__ rs) {
    const int wid = threadIdx.x >> 6, lane = threadIdx.x & 63;
    const int r = blockIdx.x * 4 + wid;            // 0..2047
    const bool isA = (r < 1024);
    const int row = isA ? r : (r - 1024);
    const float* src = (isA ? x1 : x2) + (size_t)row * 256;

    float4 g = *(const float4*)(src + 4 * lane);
    const float k = 255.0f;
    unsigned q0 = (unsigned)(k / (1.0f + __expf(-g.x)) + 0.5f);
    unsigned q1 = (unsigned)(k / (1.0f + __expf(-g.y)) + 0.5f);
    unsigned q2 = (unsigned)(k / (1.0f + __expf(-g.z)) + 0.5f);
    unsigned q3 = (unsigned)(k / (1.0f + __expf(-g.w)) + 0.5f);

    (isA ? Aq : Bq)[(size_t)row * 64 + lane] = q0 | (q1 << 8) | (q2 << 16) | (q3 << 24);

    int sum = (int)(q0 + q1 + q2 + q3);
    #pragma unroll
    for (int s = 32; s >= 1; s >>= 1)
        sum += __shfl_xor(sum, s, 64);
    if (lane == 0) rs[r] = (float)sum;             // <= 65280: f32-exact
}

// ---- main: 32x32 tiles, 256-thread blocks, 4 blocks/CU for phase overlap ----
__global__ __launch_bounds__(256, 4)
void jaccard_main(const uint4* __restrict__ Aq, const uint4* __restrict__ Bq,
                  const float* __restrict__ rs, float* __restrict__ out) {
    __shared__ char ATile[TILEB];
    __shared__ char BTile[TILEB];
    __shared__ char Part[64 * PSTR];   // [s 64][q 4][m 4] uint2

    const int bi = blockIdx.x, bj = blockIdx.y;    // 32 x 32 tiles
    const int tid = threadIdx.x;

    // ---- staging: 2 uint4 loads + 2 b128 LDS writes per thread per tile ----
    #pragma unroll
    for (int k = 0; k < 2; ++k) {
        const int flat = tid + 256 * k;            // 0..511
        const int row = flat >> 4, c16 = flat & 15;
        uint4 va = Aq[(size_t)(bi * 32 + row) * 16 + c16];
        *(uint4*)(ATile + row * RSTR + c16 * 16) = va;
        uint4 vb = Bq[(size_t)(bj * 32 + row) * 16 + c16];
        *(uint4*)(BTile + row * RSTR + c16 * 16) = vb;
    }
    __syncthreads();

    // wave = one D-quarter q (bytes [64q,64q+64)); spatial 8x8, microtile 4x4
    const int s  = tid & 63;
    const int q  = tid >> 6;        // 0..3, wave-uniform
    const int tx = s & 7;           // cols {tx + 8n}
    const int ty = s >> 3;          // rows {ty + 8m}

    const char* ab = ATile + ty * RSTR + q * 64;
    const char* bb = BTile + tx * RSTR + q * 64;

    unsigned acc[4][4] = {};
    #pragma unroll
    for (int cc = 0; cc < 4; ++cc) {               // 4 x 16B chunks per quarter
        uint4 av[4], bv[4];
        #pragma unroll
        for (int m = 0; m < 4; ++m)
            av[m] = *(const uint4*)(ab + m * (8 * RSTR) + cc * 16);   // 8-addr broadcast
        #pragma unroll
        for (int n = 0; n < 4; ++n)
            bv[n] = *(const uint4*)(bb + n * (8 * RSTR) + cc * 16);   // 8-addr broadcast
        #pragma unroll
        for (int m = 0; m < 4; ++m)
            #pragma unroll
            for (int n = 0; n < 4; ++n) {
                unsigned a = acc[m][n];
                a = sad8(av[m].x, bv[n].x, a);
                a = sad8(av[m].y, bv[n].y, a);
                a = sad8(av[m].z, bv[n].z, a);
                a = sad8(av[m].w, bv[n].w, a);
                acc[m][n] = a;
            }
    }

    // ---- partials: u16-packed [s][q][m], b64 each; 136B stride -> 2-way banks ----
    {
        char* pw = Part + s * PSTR + q * 32;
        #pragma unroll
        for (int m = 0; m < 4; ++m) {
            unsigned p0 = acc[m][0] | (acc[m][1] << 16);   // each <= 16320
            unsigned p1 = acc[m][2] | (acc[m][3] << 16);
            *(uint2*)(pw + m * 8) = make_uint2(p0, p1);
        }
    }
    __syncthreads();

    // ---- reduce + epilogue: thread (s2, m2) owns row ty2+8*m2, cols {tx2+8n} ----
    const int s2 = tid & 63;
    const int m2 = tid >> 6;
    const int tx2 = s2 & 7;
    const int ty2 = s2 >> 3;

    unsigned sd0 = 0, sd1 = 0, sd2 = 0, sd3 = 0;
    const char* pr = Part + s2 * PSTR + m2 * 8;
    #pragma unroll
    for (int qq = 0; qq < 4; ++qq) {
        uint2 p = *(const uint2*)(pr + qq * 32);
        sd0 += p.x & 0xffff; sd1 += p.x >> 16;
        sd2 += p.y & 0xffff; sd3 += p.y >> 16;
    }

    const int i  = bi * 32 + ty2 + 8 * m2;
    const int j0 = bj * 32 + tx2;

    const float sa  = rs[i];
    const float sb0 = rs[1024 + j0];
    const float sb1 = rs[1024 + j0 + 8];
    const float sb2 = rs[1024 + j0 + 16];
    const float sb3 = rs[1024 + j0 + 24];

    const float t0 = sa + sb0, t1 = sa + sb1, t2 = sa + sb2, t3 = sa + sb3;
    const float i0 = 0.5f * (t0 - (float)sd0);
    const float i1 = 0.5f * (t1 - (float)sd1);
    const float i2 = 0.5f * (t2 - (float)sd2);
    const float i3 = 0.5f * (t3 - (float)sd3);
    const float v0 = i0 / (t0 - i0);
    const float v1 = i1 / (t1 - i1);
    const float v2 = i2 / (t2 - i2);
    const float v3 = i3 / (t3 - i3);

    float* outT = out + (size_t)1024 * 1024;
    out[(size_t)i * 1024 + j0]      = v0;
    out[(size_t)i * 1024 + j0 + 8]  = v1;
    out[(size_t)i * 1024 + j0 + 16] = v2;
    out[(size_t)i * 1024 + j0 + 24] = v3;
    outT[(size_t)j0        * 1024 + i] = v0;
    outT[(size_t)(j0 + 8)  * 1024 + i] = v1;
    outT[(size_t)(j0 + 16) * 1024 + i] = v2;
    outT[(size_t)(j0 + 24) * 1024 + i] = v3;
}

extern "C" void kernel_launch(void* const* d_in, const int* in_sizes, int n_in,
                              void* d_out, int out_size, void* d_ws, size_t ws_size,
                              hipStream_t stream) {
    const float* x1 = (const float*)d_in[0];
    const float* x2 = (const float*)d_in[1];
    float* out = (float*)d_out;

    unsigned* Aq = (unsigned*)d_ws;                 // 256 KB
    unsigned* Bq = Aq + (size_t)1024 * 64;          // 256 KB
    float*    rs = (float*)(Bq + (size_t)1024 * 64);// 8 KB

    prepass<<<512, 256, 0, stream>>>(x1, x2, Aq, Bq, rs);
    jaccard_main<<<dim3(32, 32), 256, 0, stream>>>((const uint4*)Aq, (const uint4*)Bq,
                                                   rs, out);
}